// Round 11
// baseline (1065.586 us; speedup 1.0000x reference)
//
#include <hip/hip_runtime.h>

#define N_NODES 50000
#define N_EDGES 600000
#define HC 256
#define NH 8
#define AGG_BLOCKS 2048

typedef short s8v __attribute__((ext_vector_type(8)));
typedef float f4v __attribute__((ext_vector_type(4)));
typedef _Float16 h4v __attribute__((ext_vector_type(4)));
typedef _Float16 h8v __attribute__((ext_vector_type(8)));
typedef __attribute__((address_space(1))) const unsigned int as1_cu32;
typedef __attribute__((address_space(3))) unsigned int as3_u32;

__device__ inline ushort f2bf(float f) {
  unsigned u = __float_as_uint(f);
  unsigned r = u + 0x7FFF + ((u >> 16) & 1);  // RNE
  return (ushort)(r >> 16);
}

// ---------------------------------------------------------------- CSR build
__global__ void k_init_cnt(int* __restrict__ cnt) {
  int i = blockIdx.x * 256 + threadIdx.x;
  if (i < N_NODES) cnt[i] = 1;  // self-loop
}

__global__ void k_count(const int* __restrict__ dstE, int* __restrict__ cnt) {
  int e = blockIdx.x * 256 + threadIdx.x;
  if (e < N_EDGES) atomicAdd(&cnt[dstE[e]], 1);
}

__global__ void k_scan_bsum(const int* __restrict__ cnt, int* __restrict__ bsum) {
  __shared__ int sd[256];
  int i = blockIdx.x * 256 + threadIdx.x;
  sd[threadIdx.x] = (i < N_NODES) ? cnt[i] : 0;
  __syncthreads();
  for (int o = 128; o > 0; o >>= 1) {
    if (threadIdx.x < o) sd[threadIdx.x] += sd[threadIdx.x + o];
    __syncthreads();
  }
  if (threadIdx.x == 0) bsum[blockIdx.x] = sd[0];
}

__global__ void k_scan_offsets(int* __restrict__ bsum, int nb) {
  __shared__ int s[256];
  int t = threadIdx.x;
  int v = (t < nb) ? bsum[t] : 0;
  s[t] = v; __syncthreads();
  for (int o = 1; o < 256; o <<= 1) {
    int x = (t >= o) ? s[t - o] : 0;
    __syncthreads();
    s[t] += x;
    __syncthreads();
  }
  if (t < nb) bsum[t] = s[t] - v;  // exclusive
}

__global__ void k_scan_write(const int* __restrict__ cnt, const int* __restrict__ bsum,
                             int* __restrict__ rowptr, int* __restrict__ fillptr) {
  __shared__ int s[256];
  int t = threadIdx.x;
  int i = blockIdx.x * 256 + t;
  int v = (i < N_NODES) ? cnt[i] : 0;
  s[t] = v; __syncthreads();
  for (int o = 1; o < 256; o <<= 1) {
    int x = (t >= o) ? s[t - o] : 0;
    __syncthreads();
    s[t] += x;
    __syncthreads();
  }
  int excl = s[t] - v + bsum[blockIdx.x];
  if (i < N_NODES) {
    rowptr[i] = excl;
    fillptr[i] = excl;
    if (i == N_NODES - 1) rowptr[N_NODES] = excl + v;
  }
}

__global__ void k_fill(const int* __restrict__ srcE, const int* __restrict__ dstE,
                       int* __restrict__ fillptr, int* __restrict__ srcs) {
  int i = blockIdx.x * 256 + threadIdx.x;
  if (i < N_NODES) {
    int pos = atomicAdd(&fillptr[i], 1);
    srcs[pos] = i;                       // self-loop
  } else if (i < N_NODES + N_EDGES) {
    int e = i - N_NODES;
    int pos = atomicAdd(&fillptr[dstE[e]], 1);
    srcs[pos] = srcE[e];
  }
}

// ---------------------------------------------------------------- fp32 -> bf16 convert (x)
__global__ void k_cvt_x(const float* __restrict__ X, ushort* __restrict__ Xb) {
  size_t i = ((size_t)blockIdx.x * 256 + threadIdx.x) * 4;
  float4 x4 = *(const float4*)&X[i];
  ushort4 o;
  o.x = f2bf(x4.x); o.y = f2bf(x4.y); o.z = f2bf(x4.z); o.w = f2bf(x4.w);
  *(ushort4*)&Xb[i] = o;
}

// ---------------------------------------------------------------- all weight prep in ONE kernel
__global__ void k_prep(const float* __restrict__ gW0, const float* __restrict__ resW,
                       const float* __restrict__ gW1, const float* __restrict__ gW2,
                       const float* __restrict__ muW, const float* __restrict__ lvW,
                       const float* __restrict__ auxW,
                       ushort* __restrict__ WtP, ushort* __restrict__ Wt2,
                       ushort* __restrict__ Wt3, ushort* __restrict__ Wth) {
  __shared__ ushort s[32][33];
  int id = blockIdx.x;
  int t = threadIdx.x;
  if (id < 64) {                       // K=128 transposes into WtP
    const float* W = (id < 32) ? gW0 : resW;
    ushort* Wt = (id < 32) ? WtP : (WtP + 256 * 128);
    int a = id & 31;
    int bx = a & 3, by = a >> 2;       // grid (4,8)
    int tx = t & 31, ty = t >> 5;
    int k0 = bx * 32, n0 = by * 32;
    for (int j = 0; j < 32; j += 8)
      s[ty + j][tx] = f2bf(W[(size_t)(k0 + ty + j) * 256 + n0 + tx]);
    __syncthreads();
    for (int j = 0; j < 32; j += 8)
      Wt[(size_t)(n0 + ty + j) * 128 + k0 + tx] = s[tx][ty + j];
  } else if (id < 192) {               // K=256 transposes
    const float* W = (id < 128) ? gW1 : gW2;
    ushort* Wt = (id < 128) ? Wt2 : Wt3;
    int a = (id - 64) & 63;
    int bx = a & 7, by = a >> 3;       // grid (8,8)
    int tx = t & 31, ty = t >> 5;
    int k0 = bx * 32, n0 = by * 32;
    for (int j = 0; j < 32; j += 8)
      s[ty + j][tx] = f2bf(W[(size_t)(k0 + ty + j) * 256 + n0 + tx]);
    __syncthreads();
    for (int j = 0; j < 32; j += 8)
      Wt[(size_t)(n0 + ty + j) * 256 + k0 + tx] = s[tx][ty + j];
  } else {                             // pack [muW|lvW|auxW|0] -> Wth[128][256]
    int n = id - 192;                  // 0..127
    int k = t;                         // 0..255
    float v = 0.f;
    if (n < 32) v = muW[k * 32 + n];
    else if (n < 64) v = lvW[k * 32 + (n - 32)];
    else if (n < 94) v = auxW[k * 30 + (n - 64)];
    Wth[n * 256 + k] = f2bf(v);
  }
}

// ---------------------------------------------------------------- bf16 MFMA GEMM, 128x64 tile
// bias_off: cols < bias_off get 0, cols >= bias_off get bias[col - bias_off].
// Fused att epilogue: 64-col tile = 2 complete heads, one head per wave.
template <typename OutT>
__launch_bounds__(256)
__global__ void k_gemm_bf16(const ushort* __restrict__ A, const ushort* __restrict__ Wt,
                            const float* __restrict__ bias, int bias_off, OutT* __restrict__ Out,
                            int M, int K, int ldc,
                            const float* __restrict__ att_asrc, const float* __restrict__ att_adst,
                            float* __restrict__ att_as, float* __restrict__ att_ad) {
  __shared__ __align__(16) ushort As[16 * 512];  // 16 KB (A: 128 rows)
  __shared__ __align__(16) ushort Bs[8 * 512];   //  8 KB (B:  64 rows)
  int t = threadIdx.x, w = t >> 6, L = t & 63;
  int bm = blockIdx.x * 128, bn = blockIdx.y * 64;
  int lrow = L & 15, lcol = (L >> 4) * 8;

  const ushort* ga[4];
  const ushort* gb[2];
#pragma unroll
  for (int u = 0; u < 4; u++) {
    int i = w * 4 + u;
    int mt = i >> 1, ks = i & 1;
    int arow = bm + mt * 16 + lrow;
    if (arow >= M) arow = M - 1;
    ga[u] = A + (size_t)arow * K + ks * 32 + lcol;
  }
#pragma unroll
  for (int u = 0; u < 2; u++) {
    int i = w * 2 + u;
    int mt = i >> 1, ks = i & 1;
    int brow = bn + mt * 16 + lrow;
    gb[u] = Wt + (size_t)brow * K + ks * 32 + lcol;
  }

  f4v acc[4][2];
  f4v zero = {0.f, 0.f, 0.f, 0.f};
#pragma unroll
  for (int mi = 0; mi < 4; mi++)
#pragma unroll
    for (int ni = 0; ni < 2; ni++) acc[mi][ni] = zero;

  int wm = (w >> 1) * 4;
  int wn = (w & 1) * 2;

  int nk = K >> 6;
  for (int kt = 0; kt < nk; kt++) {
#pragma unroll
    for (int u = 0; u < 4; u++) {
      int i = w * 4 + u;
      __builtin_amdgcn_global_load_lds((as1_cu32*)ga[u], (as3_u32*)&As[i * 512], 16, 0, 0);
      ga[u] += 64;
    }
#pragma unroll
    for (int u = 0; u < 2; u++) {
      int i = w * 2 + u;
      __builtin_amdgcn_global_load_lds((as1_cu32*)gb[u], (as3_u32*)&Bs[i * 512], 16, 0, 0);
      gb[u] += 64;
    }
    __syncthreads();
#pragma unroll
    for (int ks = 0; ks < 2; ks++) {
      s8v af[4], bf[2];
#pragma unroll
      for (int mi = 0; mi < 4; mi++)
        af[mi] = *(const s8v*)&As[(((wm + mi) * 2 + ks) * 64 + L) * 8];
#pragma unroll
      for (int ni = 0; ni < 2; ni++)
        bf[ni] = *(const s8v*)&Bs[(((wn + ni) * 2 + ks) * 64 + L) * 8];
#pragma unroll
      for (int mi = 0; mi < 4; mi++)
#pragma unroll
        for (int ni = 0; ni < 2; ni++)
          acc[mi][ni] = __builtin_amdgcn_mfma_f32_16x16x32_bf16(af[mi], bf[ni], acc[mi][ni], 0, 0, 0);
    }
    __syncthreads();
  }
#pragma unroll
  for (int ni = 0; ni < 2; ni++) {
    int col = bn + (wn + ni) * 16 + (L & 15);
    float bb = (bias && col >= bias_off) ? bias[col - bias_off] : 0.f;
#pragma unroll
    for (int mi = 0; mi < 4; mi++) {
      int rbase = bm + (wm + mi) * 16 + (L >> 4) * 4;
#pragma unroll
      for (int i = 0; i < 4; i++) {
        int r = rbase + i;
        if (r < M) Out[(size_t)r * ldc + col] = (OutT)(acc[mi][ni][i] + bb);
      }
    }
  }
  // ---- fused attention logits (one complete head per wave) ----
  if (att_as && bn < 256) {
    int hb = ((unsigned)(bn + wn * 16)) >> 5;   // wave's head
    int cl = L & 15;
    float sa0 = att_asrc[hb * 32 + cl],  sa1 = att_asrc[hb * 32 + 16 + cl];
    float da0 = att_adst[hb * 32 + cl],  da1 = att_adst[hb * 32 + 16 + cl];
#pragma unroll
    for (int mi = 0; mi < 4; mi++) {
#pragma unroll
      for (int i = 0; i < 4; i++) {
        float vs = acc[mi][0][i] * sa0 + acc[mi][1][i] * sa1;
        float vd = acc[mi][0][i] * da0 + acc[mi][1][i] * da1;
        vs += __shfl_xor(vs, 1); vd += __shfl_xor(vd, 1);
        vs += __shfl_xor(vs, 2); vd += __shfl_xor(vd, 2);
        vs += __shfl_xor(vs, 4); vd += __shfl_xor(vd, 4);
        vs += __shfl_xor(vs, 8); vd += __shfl_xor(vd, 8);
        int r = bm + (wm + mi) * 16 + (L >> 4) * 4 + i;
        if (cl == 0 && r < M) {
          att_as[r * NH + hb] = vs;
          att_ad[r * NH + hb] = vd;
        }
      }
    }
  }
}

// ---------------------------------------------------------------- head GEMM + fused decode
__launch_bounds__(256)
__global__ void k_gemm_head(const ushort* __restrict__ A, const ushort* __restrict__ Wt,
                            const float* __restrict__ eps,
                            const float* __restrict__ mub, const float* __restrict__ lvb,
                            const float* __restrict__ auxb,
                            const float* __restrict__ decW, const float* __restrict__ decb,
                            float* __restrict__ out) {
  __shared__ __align__(16) ushort smem[16384];   // As | Bs during loop; fp16 tile after
  __shared__ float wsd[2048];                    // decW [32][64]
  __shared__ float shz[4][32];
  ushort* As = smem;
  ushort* Bs = smem + 8192;
  int t = threadIdx.x, w = t >> 6, L = t & 63;
  int bm = blockIdx.x * 128;
  int lrow = L & 15, lcol = (L >> 4) * 8;
  const int K = 256;
  for (int i = t; i < 2048; i += 256) wsd[i] = decW[i];

  const ushort* ga[4];
  const ushort* gb[4];
#pragma unroll
  for (int u = 0; u < 4; u++) {
    int i = w * 4 + u;
    int mt = i >> 1, ks = i & 1;
    int arow = bm + mt * 16 + lrow;
    if (arow >= N_NODES) arow = N_NODES - 1;
    ga[u] = A + (size_t)arow * K + ks * 32 + lcol;
    int brow = mt * 16 + lrow;                   // bn = 0, 128 rows of Wth
    gb[u] = Wt + (size_t)brow * K + ks * 32 + lcol;
  }
  f4v acc[4][4];
  f4v zero = {0.f, 0.f, 0.f, 0.f};
#pragma unroll
  for (int mi = 0; mi < 4; mi++)
#pragma unroll
    for (int ni = 0; ni < 4; ni++) acc[mi][ni] = zero;
  int wm = (w >> 1) * 4;
  int wn = (w & 1) * 4;
  for (int kt = 0; kt < 4; kt++) {
#pragma unroll
    for (int u = 0; u < 4; u++) {
      int i = w * 4 + u;
      __builtin_amdgcn_global_load_lds((as1_cu32*)ga[u], (as3_u32*)&As[i * 512], 16, 0, 0);
      __builtin_amdgcn_global_load_lds((as1_cu32*)gb[u], (as3_u32*)&Bs[i * 512], 16, 0, 0);
      ga[u] += 64; gb[u] += 64;
    }
    __syncthreads();
#pragma unroll
    for (int ks = 0; ks < 2; ks++) {
      s8v af[4], bf[4];
#pragma unroll
      for (int mi = 0; mi < 4; mi++)
        af[mi] = *(const s8v*)&As[(((wm + mi) * 2 + ks) * 64 + L) * 8];
#pragma unroll
      for (int ni = 0; ni < 4; ni++)
        bf[ni] = *(const s8v*)&Bs[(((wn + ni) * 2 + ks) * 64 + L) * 8];
#pragma unroll
      for (int mi = 0; mi < 4; mi++)
#pragma unroll
        for (int ni = 0; ni < 4; ni++)
          acc[mi][ni] = __builtin_amdgcn_mfma_f32_16x16x32_bf16(af[mi], bf[ni], acc[mi][ni], 0, 0, 0);
    }
    __syncthreads();
  }
  // stash acc -> fp16 tile [128][128] overlaying As/Bs
  _Float16* tile = (_Float16*)smem;
#pragma unroll
  for (int ni = 0; ni < 4; ni++) {
    int c = (wn + ni) * 16 + (L & 15);
#pragma unroll
    for (int mi = 0; mi < 4; mi++) {
      int rbase = (wm + mi) * 16 + (L >> 4) * 4;
#pragma unroll
      for (int i = 0; i < 4; i++)
        tile[(rbase + i) * 128 + c] = (_Float16)acc[mi][ni][i];
    }
  }
  __syncthreads();
  // decode: each wave handles 32 consecutive rows
  for (int rr = 0; rr < 32; rr++) {
    int rl = w * 32 + rr;
    int n = bm + rl;
    bool valid = n < N_NODES;
    if (L < 32) {
      float mu = (float)tile[rl * 128 + L] + mub[L];
      float lv = (float)tile[rl * 128 + 32 + L] + lvb[L];
      float zv = 0.f;
      if (valid) {
        out[(size_t)N_NODES * 64 + (size_t)n * 32 + L] = mu;
        out[(size_t)N_NODES * 96 + (size_t)n * 32 + L] = lv;
        zv = mu + eps[(size_t)n * 32 + L] * __expf(0.5f * lv);
      }
      shz[w][L] = zv;
    } else if (L < 62 && valid) {
      int j = L - 32;
      out[(size_t)N_NODES * 128 + (size_t)n * 30 + j] = (float)tile[rl * 128 + 64 + j] + auxb[j];
    }
    __syncthreads();
    float o = decb[L];
#pragma unroll 8
    for (int kk = 0; kk < 32; kk++) o += shz[w][kk] * wsd[kk * 64 + L];
    if (valid) out[(size_t)n * 64 + L] = o;
    __syncthreads();
  }
}

// ---------------------------------------------------------------- aggregate, head-sliced for XCD L2 locality
// Channel-group (== head, 32 ch, 3.2 MB slice) = blockIdx & 7: workgroups
// round-robin across the 8 XCDs, so each XCD's L2 holds only its own slice
// (fits 4 MB) instead of the whole 25.6 MB table (round-9: 52% L2 miss,
// FETCH 172 MB). Wave = node; lane = (edge-slot j = lane>>4, ch-pair q).
// Tail edges handled by guarded p=0 (no separate loop). Slot partials
// reduced via 2x shfl_xor. BN partials: 64 floats/block, direct-write
// reduction (no atomics, no stats zeroing).
__launch_bounds__(256)
__global__ void k_agg(const int* __restrict__ rowptr, const int* __restrict__ srcs,
                      const float* __restrict__ as_, const float* __restrict__ ad_,
                      const _Float16* __restrict__ B, int ld, const float* __restrict__ gb,
                      _Float16* __restrict__ C, float* __restrict__ part) {
  __shared__ float ss[4 * 64];
  int t = threadIdx.x;
  int w = t >> 6, lane = t & 63;
  int h = blockIdx.x & 7;     // head / channel-group (XCD-aligned)
  int q = lane & 15;          // channel pair within head
  int j = lane >> 4;          // edge slot
  int c = h * 32 + q * 2;
  float gb0 = gb[c], gb1 = gb[c + 1];
  float sts0 = 0.f, sts1 = 0.f, stq0 = 0.f, stq1 = 0.f;

  for (int n = (blockIdx.x >> 3) * 4 + w; n < N_NODES; n += 1024) {
    int beg = rowptr[n], end = rowptr[n + 1];
    float ad_nh = ad_[n * NH + h];
    float ac0 = 0.f, ac1 = 0.f, wsum = 0.f;
    for (int k = beg; k < end; k += 4) {
      int idx = k + j;
      bool valid = idx < end;
      if (!valid) idx = end - 1;
      int s = srcs[idx];
      float e = as_[s * NH + h] + ad_nh;
      e = e > 0.f ? e : 0.2f * e;
      float p = valid ? __expf(e) : 0.f;
      uint b2 = *(const uint*)&B[(size_t)s * ld + c];
      wsum += p;
      asm("v_fma_mix_f32 %0, %1, %2, %0 op_sel:[0,0,0] op_sel_hi:[0,1,0]"
          : "+v"(ac0) : "v"(p), "v"(b2));
      asm("v_fma_mix_f32 %0, %1, %2, %0 op_sel:[0,1,0] op_sel_hi:[0,1,0]"
          : "+v"(ac1) : "v"(p), "v"(b2));
    }
    // reduce across the 4 edge slots; all lanes end with totals
    ac0 += __shfl_xor(ac0, 16);  ac0 += __shfl_xor(ac0, 32);
    ac1 += __shfl_xor(ac1, 16);  ac1 += __shfl_xor(ac1, 32);
    wsum += __shfl_xor(wsum, 16); wsum += __shfl_xor(wsum, 32);
    float inv = 1.f / (wsum + 1e-16f);
    float v0 = ac0 * inv + gb0, v1 = ac1 * inv + gb1;
    if (lane < 16) {
      _Float16 o2[2] = {(_Float16)v0, (_Float16)v1};
      *(uint*)&C[(size_t)n * 256 + c] = *(const uint*)o2;
      sts0 += v0; stq0 += v0 * v0;
      sts1 += v1; stq1 += v1 * v1;
    }
  }
  if (lane < 16) {
    ss[w * 64 + q * 2]          = sts0;
    ss[w * 64 + q * 2 + 1]      = sts1;
    ss[w * 64 + 32 + q * 2]     = stq0;
    ss[w * 64 + 32 + q * 2 + 1] = stq1;
  }
  __syncthreads();
  if (t < 64) {
    float p0 = ss[t] + ss[64 + t] + ss[128 + t] + ss[192 + t];
    part[(size_t)blockIdx.x * 64 + t] = p0;
  }
}

// reduce AGG_BLOCKS x 64 partials -> stats[512] (direct write, no atomics)
__global__ void k_bn_reduce(const float* __restrict__ part, float* __restrict__ stats) {
  int e = blockIdx.x * 256 + threadIdx.x;   // 0..511
  int kind = e >> 8;                        // 0 = sum, 1 = sqsum
  int c = e & 255;
  int g = c >> 5, ci = c & 31;
  float s = 0.f;
  for (int jb = 0; jb < AGG_BLOCKS / 8; jb++)
    s += part[(size_t)(jb * 8 + g) * 64 + kind * 32 + ci];
  stats[e] = s;
}

// BN + ReLU (+ optional fp16 residual add, row stride rld): fp16 in -> bf16 out
// 8 channels / thread (16B loads), grid = N*HC/2048
__global__ void k_bn_relu_cvt(const _Float16* __restrict__ X, const float* __restrict__ stats,
                              const float* __restrict__ g, const float* __restrict__ b,
                              const _Float16* __restrict__ resid, int rld,
                              ushort* __restrict__ Xb) {
  size_t i = ((size_t)blockIdx.x * 256 + threadIdx.x) * 8;
  int c = (int)(i & 255);
  const float invN = 1.f / (float)N_NODES;
  h8v x8 = *(const h8v*)&X[i];
  float v[8];
#pragma unroll
  for (int q = 0; q < 2; q++) {
    float4 s4 = *(const float4*)&stats[c + q * 4];
    float4 q4 = *(const float4*)&stats[256 + c + q * 4];
    float4 g4 = *(const float4*)&g[c + q * 4];
    float4 b4 = *(const float4*)&b[c + q * 4];
    float m0 = s4.x * invN, m1 = s4.y * invN, m2 = s4.z * invN, m3 = s4.w * invN;
    v[q * 4 + 0] = ((float)x8[q * 4 + 0] - m0) * rsqrtf(q4.x * invN - m0 * m0 + 1e-5f) * g4.x + b4.x;
    v[q * 4 + 1] = ((float)x8[q * 4 + 1] - m1) * rsqrtf(q4.y * invN - m1 * m1 + 1e-5f) * g4.y + b4.y;
    v[q * 4 + 2] = ((float)x8[q * 4 + 2] - m2) * rsqrtf(q4.z * invN - m2 * m2 + 1e-5f) * g4.z + b4.z;
    v[q * 4 + 3] = ((float)x8[q * 4 + 3] - m3) * rsqrtf(q4.w * invN - m3 * m3 + 1e-5f) * g4.w + b4.w;
  }
#pragma unroll
  for (int q = 0; q < 8; q++) v[q] = v[q] > 0.f ? v[q] : 0.f;
  if (resid) {
    size_t row = i >> 8;
    h8v r8 = *(const h8v*)&resid[row * rld + c];
#pragma unroll
    for (int q = 0; q < 8; q++) v[q] += (float)r8[q];
  }
  ushort o8[8];
#pragma unroll
  for (int q = 0; q < 8; q++) o8[q] = f2bf(v[q]);
  *(uint4*)&Xb[i] = *(const uint4*)o8;
}

// ---------------------------------------------------------------- launch
extern "C" void kernel_launch(void* const* d_in, const int* in_sizes, int n_in,
                              void* d_out, int out_size, void* d_ws, size_t ws_size,
                              hipStream_t stream) {
  (void)in_sizes; (void)n_in; (void)out_size; (void)ws_size;
  const float* x    = (const float*)d_in[0];
  const float* eps  = (const float*)d_in[1];
  const int*   ei   = (const int*)d_in[2];
  const float* gW[3]    = {(const float*)d_in[3],  (const float*)d_in[9],  (const float*)d_in[15]};
  const float* gasrc[3] = {(const float*)d_in[4],  (const float*)d_in[10], (const float*)d_in[16]};
  const float* gadst[3] = {(const float*)d_in[5],  (const float*)d_in[11], (const float*)d_in[17]};
  const float* gbias[3] = {(const float*)d_in[6],  (const float*)d_in[12], (const float*)d_in[18]};
  const float* bng[3]   = {(const float*)d_in[7],  (const float*)d_in[13], (const float*)d_in[19]};
  const float* bnb[3]   = {(const float*)d_in[8],  (const float*)d_in[14], (const float*)d_in[20]};
  const float* resW = (const float*)d_in[21];
  const float* resb = (const float*)d_in[22];
  const float* muW  = (const float*)d_in[23];
  const float* mub  = (const float*)d_in[24];
  const float* lvW  = (const float*)d_in[25];
  const float* lvb  = (const float*)d_in[26];
  const float* decW = (const float*)d_in[27];
  const float* decb = (const float*)d_in[28];
  const float* auxW = (const float*)d_in[29];
  const float* auxb = (const float*)d_in[30];
  float* out = (float*)d_out;

  char* ws = (char*)d_ws;
  size_t off = 0;
  auto alloc = [&](size_t bytes) -> void* {
    void* p = ws + off;
    off += (bytes + 255) & ~(size_t)255;
    return p;
  };
  _Float16* X0R = (_Float16*)alloc((size_t)N_NODES * 512 * 2); // layer1 GEMM out [gat1|residual] (fp16)
  _Float16* X0  = (_Float16*)alloc((size_t)N_NODES * HC * 2);  // layer2/3 GEMM out (fp16)
  _Float16* X1  = (_Float16*)alloc((size_t)N_NODES * HC * 2);  // agg output (fp16)
  ushort* Xb    = (ushort*)alloc((size_t)N_NODES * HC * 2);    // bf16 activations
  float*  as_   = (float*)alloc((size_t)N_NODES * NH * 4);
  float*  ad_   = (float*)alloc((size_t)N_NODES * NH * 4);
  float*  stats = (float*)alloc(512 * 4);
  float*  part  = (float*)alloc((size_t)AGG_BLOCKS * 64 * 4);  // BN partials (head-sliced)
  int* cnt      = (int*)alloc((size_t)N_NODES * 4);
  int* rowptr   = (int*)alloc((size_t)(N_NODES + 1) * 4);
  int* fillptr  = (int*)alloc((size_t)N_NODES * 4);
  int* srcs     = (int*)alloc((size_t)(N_NODES + N_EDGES) * 4);
  int* bsum     = (int*)alloc(256 * 4);
  ushort* WtP   = (ushort*)alloc(512 * 128 * 2);  // [gat1_Wt ; res_Wt]
  ushort* Wt2   = (ushort*)alloc(256 * 256 * 2);
  ushort* Wt3   = (ushort*)alloc(256 * 256 * 2);
  ushort* Wth   = (ushort*)alloc(128 * 256 * 2);

  const int NB = (N_NODES + 255) / 256;
  // CSR build
  k_init_cnt<<<NB, 256, 0, stream>>>(cnt);
  k_count<<<(N_EDGES + 255) / 256, 256, 0, stream>>>(ei + N_EDGES, cnt);
  k_scan_bsum<<<NB, 256, 0, stream>>>(cnt, bsum);
  k_scan_offsets<<<1, 256, 0, stream>>>(bsum, NB);
  k_scan_write<<<NB, 256, 0, stream>>>(cnt, bsum, rowptr, fillptr);
  k_fill<<<(N_NODES + N_EDGES + 255) / 256, 256, 0, stream>>>(ei, ei + N_EDGES, fillptr, srcs);

  // weight prep (one kernel) + x -> bf16
  k_prep<<<320, 256, 0, stream>>>(gW[0], resW, gW[1], gW[2], muW, lvW, auxW, WtP, Wt2, Wt3, Wth);
  k_cvt_x<<<(N_NODES * 128) / 1024, 256, 0, stream>>>(x, Xb);

  const int GM = (N_NODES + 127) / 128;  // 391
  const int EW_GRID = (N_NODES * HC) / 2048;  // 6250

  // layer 1 + residual fused (+ att epilogue on cols 0-255); N=512 -> 8 col-tiles
  k_gemm_bf16<_Float16><<<dim3(GM, 8), 256, 0, stream>>>(
      Xb, WtP, resb, 256, X0R, N_NODES, 128, 512, gasrc[0], gadst[0], as_, ad_);
  k_agg<<<AGG_BLOCKS, 256, 0, stream>>>(rowptr, srcs, as_, ad_, X0R, 512, gbias[0], X1, part);
  k_bn_reduce<<<2, 256, 0, stream>>>(part, stats);
  k_bn_relu_cvt<<<EW_GRID, 256, 0, stream>>>(X1, stats, bng[0], bnb[0], nullptr, 0, Xb);

  // layers 2, 3 (+ att epilogue); N=256 -> 4 col-tiles
  const ushort* Wts[2] = {Wt2, Wt3};
  for (int L = 0; L < 2; L++) {
    k_gemm_bf16<_Float16><<<dim3(GM, 4), 256, 0, stream>>>(
        Xb, Wts[L], nullptr, 0, X0, N_NODES, 256, 256, gasrc[L + 1], gadst[L + 1], as_, ad_);
    k_agg<<<AGG_BLOCKS, 256, 0, stream>>>(rowptr, srcs, as_, ad_, X0, 256, gbias[L + 1], X1, part);
    k_bn_reduce<<<2, 256, 0, stream>>>(part, stats);
    k_bn_relu_cvt<<<EW_GRID, 256, 0, stream>>>(
        X1, stats, bng[L + 1], bnb[L + 1], (L == 1) ? (X0R + 256) : nullptr, 512, Xb);
  }
  // head GEMM + fused decode epilogue
  k_gemm_head<<<GM, 256, 0, stream>>>(Xb, Wth, eps, mub, lvb, auxb, decW, decb, out);
}

// Round 12
// 633.873 us; speedup vs baseline: 1.6811x; 1.6811x over previous
//
#include <hip/hip_runtime.h>

#define N_NODES 50000
#define N_EDGES 600000
#define HC 256
#define NH 8
#define AGG_BLOCKS 2048
#define AGG_WAVES (AGG_BLOCKS * 4)

typedef short s8v __attribute__((ext_vector_type(8)));
typedef float f4v __attribute__((ext_vector_type(4)));
typedef _Float16 h4v __attribute__((ext_vector_type(4)));
typedef _Float16 h8v __attribute__((ext_vector_type(8)));
typedef __attribute__((address_space(1))) const unsigned int as1_cu32;
typedef __attribute__((address_space(3))) unsigned int as3_u32;

__device__ inline ushort f2bf(float f) {
  unsigned u = __float_as_uint(f);
  unsigned r = u + 0x7FFF + ((u >> 16) & 1);  // RNE
  return (ushort)(r >> 16);
}

// ---------------------------------------------------------------- CSR build
__global__ void k_init_cnt(int* __restrict__ cnt) {
  int i = blockIdx.x * 256 + threadIdx.x;
  if (i < N_NODES) cnt[i] = 1;  // self-loop
}

__global__ void k_count(const int* __restrict__ dstE, int* __restrict__ cnt) {
  int e = blockIdx.x * 256 + threadIdx.x;
  if (e < N_EDGES) atomicAdd(&cnt[dstE[e]], 1);
}

__global__ void k_scan_bsum(const int* __restrict__ cnt, int* __restrict__ bsum) {
  __shared__ int sd[256];
  int i = blockIdx.x * 256 + threadIdx.x;
  sd[threadIdx.x] = (i < N_NODES) ? cnt[i] : 0;
  __syncthreads();
  for (int o = 128; o > 0; o >>= 1) {
    if (threadIdx.x < o) sd[threadIdx.x] += sd[threadIdx.x + o];
    __syncthreads();
  }
  if (threadIdx.x == 0) bsum[blockIdx.x] = sd[0];
}

__global__ void k_scan_offsets(int* __restrict__ bsum, int nb) {
  __shared__ int s[256];
  int t = threadIdx.x;
  int v = (t < nb) ? bsum[t] : 0;
  s[t] = v; __syncthreads();
  for (int o = 1; o < 256; o <<= 1) {
    int x = (t >= o) ? s[t - o] : 0;
    __syncthreads();
    s[t] += x;
    __syncthreads();
  }
  if (t < nb) bsum[t] = s[t] - v;  // exclusive
}

__global__ void k_scan_write(const int* __restrict__ cnt, const int* __restrict__ bsum,
                             int* __restrict__ rowptr, int* __restrict__ fillptr) {
  __shared__ int s[256];
  int t = threadIdx.x;
  int i = blockIdx.x * 256 + t;
  int v = (i < N_NODES) ? cnt[i] : 0;
  s[t] = v; __syncthreads();
  for (int o = 1; o < 256; o <<= 1) {
    int x = (t >= o) ? s[t - o] : 0;
    __syncthreads();
    s[t] += x;
    __syncthreads();
  }
  int excl = s[t] - v + bsum[blockIdx.x];
  if (i < N_NODES) {
    rowptr[i] = excl;
    fillptr[i] = excl;
    if (i == N_NODES - 1) rowptr[N_NODES] = excl + v;
  }
}

__global__ void k_fill(const int* __restrict__ srcE, const int* __restrict__ dstE,
                       int* __restrict__ fillptr, int* __restrict__ srcs) {
  int i = blockIdx.x * 256 + threadIdx.x;
  if (i < N_NODES) {
    int pos = atomicAdd(&fillptr[i], 1);
    srcs[pos] = i;                       // self-loop
  } else if (i < N_NODES + N_EDGES) {
    int e = i - N_NODES;
    int pos = atomicAdd(&fillptr[dstE[e]], 1);
    srcs[pos] = srcE[e];
  }
}

// ---------------------------------------------------------------- fp32 -> bf16 convert (x)
__global__ void k_cvt_x(const float* __restrict__ X, ushort* __restrict__ Xb) {
  size_t i = ((size_t)blockIdx.x * 256 + threadIdx.x) * 4;
  float4 x4 = *(const float4*)&X[i];
  ushort4 o;
  o.x = f2bf(x4.x); o.y = f2bf(x4.y); o.z = f2bf(x4.z); o.w = f2bf(x4.w);
  *(ushort4*)&Xb[i] = o;
}

// ---------------------------------------------------------------- all weight prep in ONE kernel
__global__ void k_prep(const float* __restrict__ gW0, const float* __restrict__ resW,
                       const float* __restrict__ gW1, const float* __restrict__ gW2,
                       const float* __restrict__ muW, const float* __restrict__ lvW,
                       const float* __restrict__ auxW,
                       ushort* __restrict__ WtP, ushort* __restrict__ Wt2,
                       ushort* __restrict__ Wt3, ushort* __restrict__ Wth) {
  __shared__ ushort s[32][33];
  int id = blockIdx.x;
  int t = threadIdx.x;
  if (id < 64) {                       // K=128 transposes into WtP
    const float* W = (id < 32) ? gW0 : resW;
    ushort* Wt = (id < 32) ? WtP : (WtP + 256 * 128);
    int a = id & 31;
    int bx = a & 3, by = a >> 2;       // grid (4,8)
    int tx = t & 31, ty = t >> 5;
    int k0 = bx * 32, n0 = by * 32;
    for (int j = 0; j < 32; j += 8)
      s[ty + j][tx] = f2bf(W[(size_t)(k0 + ty + j) * 256 + n0 + tx]);
    __syncthreads();
    for (int j = 0; j < 32; j += 8)
      Wt[(size_t)(n0 + ty + j) * 128 + k0 + tx] = s[tx][ty + j];
  } else if (id < 192) {               // K=256 transposes
    const float* W = (id < 128) ? gW1 : gW2;
    ushort* Wt = (id < 128) ? Wt2 : Wt3;
    int a = (id - 64) & 63;
    int bx = a & 7, by = a >> 3;       // grid (8,8)
    int tx = t & 31, ty = t >> 5;
    int k0 = bx * 32, n0 = by * 32;
    for (int j = 0; j < 32; j += 8)
      s[ty + j][tx] = f2bf(W[(size_t)(k0 + ty + j) * 256 + n0 + tx]);
    __syncthreads();
    for (int j = 0; j < 32; j += 8)
      Wt[(size_t)(n0 + ty + j) * 256 + k0 + tx] = s[tx][ty + j];
  } else {                             // pack [muW|lvW|auxW|0] -> Wth[128][256]
    int n = id - 192;                  // 0..127
    int k = t;                         // 0..255
    float v = 0.f;
    if (n < 32) v = muW[k * 32 + n];
    else if (n < 64) v = lvW[k * 32 + (n - 32)];
    else if (n < 94) v = auxW[k * 30 + (n - 64)];
    Wth[n * 256 + k] = f2bf(v);
  }
}

// ---------------------------------------------------------------- bf16 MFMA GEMM, 128x64 tile,
// B K-panel resident in LDS (one barrier total), A fragments read DIRECTLY
// from global in the K-loop (per-lane 16B, 64B/row segments; step offsets fold
// into the load immediate). No __syncthreads in the K-loop -> the short-nk
// barrier-drain stall (round-7: MfmaUtil 3.7%) is structurally removed;
// latency hidden by ~5 resident blocks (LDS 16-32KB).
// Fused att epilogue: 64-col tile = 2 complete heads, one head per wave.
template <int K, typename OutT>
__launch_bounds__(256)
__global__ void k_gemm_bf16(const ushort* __restrict__ A, const ushort* __restrict__ Wt,
                            const float* __restrict__ bias, int bias_off, OutT* __restrict__ Out,
                            int M, int ldc,
                            const float* __restrict__ att_asrc, const float* __restrict__ att_adst,
                            float* __restrict__ att_as, float* __restrict__ att_ad) {
  constexpr int S = K / 32;                      // k-steps
  __shared__ __align__(16) ushort Bs[4 * S * 512];  // 4 row-groups x S steps x 64 lanes x 8
  int t = threadIdx.x, w = t >> 6, L = t & 63;
  int bm = blockIdx.x * 128, bn = blockIdx.y * 64;
  int lrow = L & 15, lcol = (L >> 4) * 8;

  // stage FULL B panel: wave w stages row-group w (rows bn+w*16+lrow), S chunks
  {
    const ushort* gsrc = Wt + (size_t)(bn + w * 16 + lrow) * K + lcol;
#pragma unroll
    for (int s = 0; s < S; s++) {
      __builtin_amdgcn_global_load_lds((as1_cu32*)(gsrc + s * 32),
                                       (as3_u32*)&Bs[(w * S + s) * 512], 16, 0, 0);
    }
  }

  // A row pointers (direct-from-global fragments)
  const ushort* pa[4];
  int wm = (w >> 1) * 4;
  int wn = (w & 1) * 2;
#pragma unroll
  for (int mi = 0; mi < 4; mi++) {
    int r = bm + (wm + mi) * 16 + lrow;
    if (r >= M) r = M - 1;
    pa[mi] = A + (size_t)r * K + lcol;
  }

  f4v acc[4][2];
  f4v zero = {0.f, 0.f, 0.f, 0.f};
#pragma unroll
  for (int mi = 0; mi < 4; mi++)
#pragma unroll
    for (int ni = 0; ni < 2; ni++) acc[mi][ni] = zero;

  __syncthreads();  // B panel ready (single barrier; gld_lds drained by the implicit waitcnt)

#pragma unroll
  for (int s = 0; s < S; s++) {
    s8v af[4], bf[2];
#pragma unroll
    for (int mi = 0; mi < 4; mi++)
      af[mi] = *(const s8v*)(pa[mi] + s * 32);
#pragma unroll
    for (int ni = 0; ni < 2; ni++)
      bf[ni] = *(const s8v*)&Bs[(((wn + ni) * S + s) * 64 + L) * 8];
#pragma unroll
    for (int mi = 0; mi < 4; mi++)
#pragma unroll
      for (int ni = 0; ni < 2; ni++)
        acc[mi][ni] = __builtin_amdgcn_mfma_f32_16x16x32_bf16(af[mi], bf[ni], acc[mi][ni], 0, 0, 0);
  }

#pragma unroll
  for (int ni = 0; ni < 2; ni++) {
    int col = bn + (wn + ni) * 16 + (L & 15);
    float bb = (bias && col >= bias_off) ? bias[col - bias_off] : 0.f;
#pragma unroll
    for (int mi = 0; mi < 4; mi++) {
      int rbase = bm + (wm + mi) * 16 + (L >> 4) * 4;
#pragma unroll
      for (int i = 0; i < 4; i++) {
        int r = rbase + i;
        if (r < M) Out[(size_t)r * ldc + col] = (OutT)(acc[mi][ni][i] + bb);
      }
    }
  }
  // ---- fused attention logits (one complete head per wave) ----
  if (att_as && bn < 256) {
    int hb = ((unsigned)(bn + wn * 16)) >> 5;   // wave's head
    int cl = L & 15;
    float sa0 = att_asrc[hb * 32 + cl],  sa1 = att_asrc[hb * 32 + 16 + cl];
    float da0 = att_adst[hb * 32 + cl],  da1 = att_adst[hb * 32 + 16 + cl];
#pragma unroll
    for (int mi = 0; mi < 4; mi++) {
#pragma unroll
      for (int i = 0; i < 4; i++) {
        float vs = acc[mi][0][i] * sa0 + acc[mi][1][i] * sa1;
        float vd = acc[mi][0][i] * da0 + acc[mi][1][i] * da1;
        vs += __shfl_xor(vs, 1); vd += __shfl_xor(vd, 1);
        vs += __shfl_xor(vs, 2); vd += __shfl_xor(vd, 2);
        vs += __shfl_xor(vs, 4); vd += __shfl_xor(vd, 4);
        vs += __shfl_xor(vs, 8); vd += __shfl_xor(vd, 8);
        int r = bm + (wm + mi) * 16 + (L >> 4) * 4 + i;
        if (cl == 0 && r < M) {
          att_as[r * NH + hb] = vs;
          att_ad[r * NH + hb] = vd;
        }
      }
    }
  }
}

// ---------------------------------------------------------------- head GEMM + fused decode
__launch_bounds__(256)
__global__ void k_gemm_head(const ushort* __restrict__ A, const ushort* __restrict__ Wt,
                            const float* __restrict__ eps,
                            const float* __restrict__ mub, const float* __restrict__ lvb,
                            const float* __restrict__ auxb,
                            const float* __restrict__ decW, const float* __restrict__ decb,
                            float* __restrict__ out) {
  __shared__ __align__(16) ushort smem[16384];   // As | Bs during loop; fp16 tile after
  __shared__ float wsd[2048];                    // decW [32][64]
  __shared__ float shz[4][32];
  ushort* As = smem;
  ushort* Bs = smem + 8192;
  int t = threadIdx.x, w = t >> 6, L = t & 63;
  int bm = blockIdx.x * 128;
  int lrow = L & 15, lcol = (L >> 4) * 8;
  const int K = 256;
  for (int i = t; i < 2048; i += 256) wsd[i] = decW[i];

  const ushort* ga[4];
  const ushort* gb[4];
#pragma unroll
  for (int u = 0; u < 4; u++) {
    int i = w * 4 + u;
    int mt = i >> 1, ks = i & 1;
    int arow = bm + mt * 16 + lrow;
    if (arow >= N_NODES) arow = N_NODES - 1;
    ga[u] = A + (size_t)arow * K + ks * 32 + lcol;
    int brow = mt * 16 + lrow;                   // bn = 0, 128 rows of Wth
    gb[u] = Wt + (size_t)brow * K + ks * 32 + lcol;
  }
  f4v acc[4][4];
  f4v zero = {0.f, 0.f, 0.f, 0.f};
#pragma unroll
  for (int mi = 0; mi < 4; mi++)
#pragma unroll
    for (int ni = 0; ni < 4; ni++) acc[mi][ni] = zero;
  int wm = (w >> 1) * 4;
  int wn = (w & 1) * 4;
  for (int kt = 0; kt < 4; kt++) {
#pragma unroll
    for (int u = 0; u < 4; u++) {
      int i = w * 4 + u;
      __builtin_amdgcn_global_load_lds((as1_cu32*)ga[u], (as3_u32*)&As[i * 512], 16, 0, 0);
      __builtin_amdgcn_global_load_lds((as1_cu32*)gb[u], (as3_u32*)&Bs[i * 512], 16, 0, 0);
      ga[u] += 64; gb[u] += 64;
    }
    __syncthreads();
#pragma unroll
    for (int ks = 0; ks < 2; ks++) {
      s8v af[4], bf[4];
#pragma unroll
      for (int mi = 0; mi < 4; mi++)
        af[mi] = *(const s8v*)&As[(((wm + mi) * 2 + ks) * 64 + L) * 8];
#pragma unroll
      for (int ni = 0; ni < 4; ni++)
        bf[ni] = *(const s8v*)&Bs[(((wn + ni) * 2 + ks) * 64 + L) * 8];
#pragma unroll
      for (int mi = 0; mi < 4; mi++)
#pragma unroll
        for (int ni = 0; ni < 4; ni++)
          acc[mi][ni] = __builtin_amdgcn_mfma_f32_16x16x32_bf16(af[mi], bf[ni], acc[mi][ni], 0, 0, 0);
    }
    __syncthreads();
  }
  // stash acc -> fp16 tile [128][128] overlaying As/Bs
  _Float16* tile = (_Float16*)smem;
#pragma unroll
  for (int ni = 0; ni < 4; ni++) {
    int c = (wn + ni) * 16 + (L & 15);
#pragma unroll
    for (int mi = 0; mi < 4; mi++) {
      int rbase = (wm + mi) * 16 + (L >> 4) * 4;
#pragma unroll
      for (int i = 0; i < 4; i++)
        tile[(rbase + i) * 128 + c] = (_Float16)acc[mi][ni][i];
    }
  }
  __syncthreads();
  // decode: each wave handles 32 consecutive rows
  for (int rr = 0; rr < 32; rr++) {
    int rl = w * 32 + rr;
    int n = bm + rl;
    bool valid = n < N_NODES;
    if (L < 32) {
      float mu = (float)tile[rl * 128 + L] + mub[L];
      float lv = (float)tile[rl * 128 + 32 + L] + lvb[L];
      float zv = 0.f;
      if (valid) {
        out[(size_t)N_NODES * 64 + (size_t)n * 32 + L] = mu;
        out[(size_t)N_NODES * 96 + (size_t)n * 32 + L] = lv;
        zv = mu + eps[(size_t)n * 32 + L] * __expf(0.5f * lv);
      }
      shz[w][L] = zv;
    } else if (L < 62 && valid) {
      int j = L - 32;
      out[(size_t)N_NODES * 128 + (size_t)n * 30 + j] = (float)tile[rl * 128 + 64 + j] + auxb[j];
    }
    __syncthreads();
    float o = decb[L];
#pragma unroll 8
    for (int kk = 0; kk < 32; kk++) o += shz[w][kk] * wsd[kk * 64 + L];
    if (valid) out[(size_t)n * 64 + L] = o;
    __syncthreads();
  }
}

// ---------------------------------------------------------------- aggregate (round-9 form; at its fabric floor)
#define FMA4(P, B2)                                                                        \
  asm("v_fma_mix_f32 %0, %1, %2, %0 op_sel:[0,0,0] op_sel_hi:[0,1,0]"                      \
      : "+v"(ac0) : "v"(P), "v"((B2).x));                                                  \
  asm("v_fma_mix_f32 %0, %1, %2, %0 op_sel:[0,1,0] op_sel_hi:[0,1,0]"                      \
      : "+v"(ac1) : "v"(P), "v"((B2).x));                                                  \
  asm("v_fma_mix_f32 %0, %1, %2, %0 op_sel:[0,0,0] op_sel_hi:[0,1,0]"                      \
      : "+v"(ac2) : "v"(P), "v"((B2).y));                                                  \
  asm("v_fma_mix_f32 %0, %1, %2, %0 op_sel:[0,1,0] op_sel_hi:[0,1,0]"                      \
      : "+v"(ac3) : "v"(P), "v"((B2).y));

__launch_bounds__(256)
__global__ void k_agg(const int* __restrict__ rowptr, const int* __restrict__ srcs,
                      const float* __restrict__ as_, const float* __restrict__ ad_,
                      const _Float16* __restrict__ B, int ld, const float* __restrict__ gb,
                      _Float16* __restrict__ C, float* __restrict__ part,
                      float* __restrict__ stats) {
  __shared__ float ss[4 * 512];
  int t = threadIdx.x;
  if (blockIdx.x == 0) {  // fold stats zeroing (consumed only by k_bn_reduce, after this kernel)
    stats[t] = 0.f; stats[t + 256] = 0.f;
  }
  int w = t >> 6, lane = t & 63;
  int h = lane >> 3;
  int cb = lane << 2;     // 4 channels per lane
  int ldu = ld >> 2;      // row stride in uint2 (8B) units
  const uint2* Bu = (const uint2*)B;
  float4 g4 = *(const float4*)&gb[cb];
  float sts0 = 0.f, sts1 = 0.f, sts2 = 0.f, sts3 = 0.f;
  float stq0 = 0.f, stq1 = 0.f, stq2 = 0.f, stq3 = 0.f;

  for (int n = blockIdx.x * 4 + w; n < N_NODES; n += AGG_WAVES) {
    int beg = rowptr[n], end = rowptr[n + 1];
    float ad_nh = ad_[n * NH + h];
    float ac0 = 0.f, ac1 = 0.f, ac2 = 0.f, ac3 = 0.f, wsum = 0.f;
    int k = beg;
    for (; k + 4 <= end; k += 4) {
      int s0 = srcs[k], s1 = srcs[k + 1], s2 = srcs[k + 2], s3 = srcs[k + 3];
      uint2 b0 = Bu[(size_t)s0 * ldu + lane];
      uint2 b1 = Bu[(size_t)s1 * ldu + lane];
      uint2 b2 = Bu[(size_t)s2 * ldu + lane];
      uint2 b3 = Bu[(size_t)s3 * ldu + lane];
      float e0 = as_[s0 * NH + h] + ad_nh; e0 = e0 > 0.f ? e0 : 0.2f * e0;
      float e1 = as_[s1 * NH + h] + ad_nh; e1 = e1 > 0.f ? e1 : 0.2f * e1;
      float e2 = as_[s2 * NH + h] + ad_nh; e2 = e2 > 0.f ? e2 : 0.2f * e2;
      float e3 = as_[s3 * NH + h] + ad_nh; e3 = e3 > 0.f ? e3 : 0.2f * e3;
      float p0 = __expf(e0), p1 = __expf(e1), p2 = __expf(e2), p3 = __expf(e3);
      wsum += (p0 + p1) + (p2 + p3);
      FMA4(p0, b0)
      FMA4(p1, b1)
      FMA4(p2, b2)
      FMA4(p3, b3)
    }
    for (; k < end; k++) {
      int s = srcs[k];
      h4v b4 = *(const h4v*)&B[(size_t)s * ld + cb];
      float e = as_[s * NH + h] + ad_nh;
      e = e > 0.f ? e : 0.2f * e;
      float p = __expf(e);
      wsum += p;
      ac0 += p * (float)b4[0]; ac1 += p * (float)b4[1];
      ac2 += p * (float)b4[2]; ac3 += p * (float)b4[3];
    }
    float inv = 1.f / (wsum + 1e-16f);
    float v0 = ac0 * inv + g4.x, v1 = ac1 * inv + g4.y;
    float v2 = ac2 * inv + g4.z, v3 = ac3 * inv + g4.w;
    h4v o; o[0] = (_Float16)v0; o[1] = (_Float16)v1; o[2] = (_Float16)v2; o[3] = (_Float16)v3;
    *(h4v*)&C[(size_t)n * 256 + cb] = o;
    sts0 += v0; stq0 += v0 * v0;
    sts1 += v1; stq1 += v1 * v1;
    sts2 += v2; stq2 += v2 * v2;
    sts3 += v3; stq3 += v3 * v3;
  }
  // per-wave LDS slots (no atomics), cross-wave sum, plain store of partials
  float* sw = &ss[w * 512];
  sw[cb + 0] = sts0; sw[cb + 1] = sts1; sw[cb + 2] = sts2; sw[cb + 3] = sts3;
  sw[256 + cb + 0] = stq0; sw[256 + cb + 1] = stq1;
  sw[256 + cb + 2] = stq2; sw[256 + cb + 3] = stq3;
  __syncthreads();
  float p0 = ss[t] + ss[512 + t] + ss[1024 + t] + ss[1536 + t];
  float p1 = ss[256 + t] + ss[768 + t] + ss[1280 + t] + ss[1792 + t];
  part[(size_t)blockIdx.x * 512 + t] = p0;
  part[(size_t)blockIdx.x * 512 + 256 + t] = p1;
}

// reduce AGG_BLOCKS x 512 partials -> stats[512]; 16 blocks, tiny atomic fan-in
__global__ void k_bn_reduce(const float* __restrict__ part, float* __restrict__ stats) {
  int i = threadIdx.x;            // 0..255
  int base = blockIdx.x * (AGG_BLOCKS / 16);
  float s0 = 0.f, s1 = 0.f;
  for (int b = 0; b < AGG_BLOCKS / 16; b++) {
    s0 += part[(size_t)(base + b) * 512 + i];
    s1 += part[(size_t)(base + b) * 512 + 256 + i];
  }
  atomicAdd(&stats[i], s0);
  atomicAdd(&stats[256 + i], s1);
}

// BN + ReLU (+ optional fp16 residual add, row stride rld): fp16 in -> bf16 out
// 8 channels / thread (16B loads), grid = N*HC/2048
__global__ void k_bn_relu_cvt(const _Float16* __restrict__ X, const float* __restrict__ stats,
                              const float* __restrict__ g, const float* __restrict__ b,
                              const _Float16* __restrict__ resid, int rld,
                              ushort* __restrict__ Xb) {
  size_t i = ((size_t)blockIdx.x * 256 + threadIdx.x) * 8;
  int c = (int)(i & 255);
  const float invN = 1.f / (float)N_NODES;
  h8v x8 = *(const h8v*)&X[i];
  float v[8];
#pragma unroll
  for (int q = 0; q < 2; q++) {
    float4 s4 = *(const float4*)&stats[c + q * 4];
    float4 q4 = *(const float4*)&stats[256 + c + q * 4];
    float4 g4 = *(const float4*)&g[c + q * 4];
    float4 b4 = *(const float4*)&b[c + q * 4];
    float m0 = s4.x * invN, m1 = s4.y * invN, m2 = s4.z * invN, m3 = s4.w * invN;
    v[q * 4 + 0] = ((float)x8[q * 4 + 0] - m0) * rsqrtf(q4.x * invN - m0 * m0 + 1e-5f) * g4.x + b4.x;
    v[q * 4 + 1] = ((float)x8[q * 4 + 1] - m1) * rsqrtf(q4.y * invN - m1 * m1 + 1e-5f) * g4.y + b4.y;
    v[q * 4 + 2] = ((float)x8[q * 4 + 2] - m2) * rsqrtf(q4.z * invN - m2 * m2 + 1e-5f) * g4.z + b4.z;
    v[q * 4 + 3] = ((float)x8[q * 4 + 3] - m3) * rsqrtf(q4.w * invN - m3 * m3 + 1e-5f) * g4.w + b4.w;
  }
#pragma unroll
  for (int q = 0; q < 8; q++) v[q] = v[q] > 0.f ? v[q] : 0.f;
  if (resid) {
    size_t row = i >> 8;
    h8v r8 = *(const h8v*)&resid[row * rld + c];
#pragma unroll
    for (int q = 0; q < 8; q++) v[q] += (float)r8[q];
  }
  ushort o8[8];
#pragma unroll
  for (int q = 0; q < 8; q++) o8[q] = f2bf(v[q]);
  *(uint4*)&Xb[i] = *(const uint4*)o8;
}

// ---------------------------------------------------------------- launch
extern "C" void kernel_launch(void* const* d_in, const int* in_sizes, int n_in,
                              void* d_out, int out_size, void* d_ws, size_t ws_size,
                              hipStream_t stream) {
  (void)in_sizes; (void)n_in; (void)out_size; (void)ws_size;
  const float* x    = (const float*)d_in[0];
  const float* eps  = (const float*)d_in[1];
  const int*   ei   = (const int*)d_in[2];
  const float* gW[3]    = {(const float*)d_in[3],  (const float*)d_in[9],  (const float*)d_in[15]};
  const float* gasrc[3] = {(const float*)d_in[4],  (const float*)d_in[10], (const float*)d_in[16]};
  const float* gadst[3] = {(const float*)d_in[5],  (const float*)d_in[11], (const float*)d_in[17]};
  const float* gbias[3] = {(const float*)d_in[6],  (const float*)d_in[12], (const float*)d_in[18]};
  const float* bng[3]   = {(const float*)d_in[7],  (const float*)d_in[13], (const float*)d_in[19]};
  const float* bnb[3]   = {(const float*)d_in[8],  (const float*)d_in[14], (const float*)d_in[20]};
  const float* resW = (const float*)d_in[21];
  const float* resb = (const float*)d_in[22];
  const float* muW  = (const float*)d_in[23];
  const float* mub  = (const float*)d_in[24];
  const float* lvW  = (const float*)d_in[25];
  const float* lvb  = (const float*)d_in[26];
  const float* decW = (const float*)d_in[27];
  const float* decb = (const float*)d_in[28];
  const float* auxW = (const float*)d_in[29];
  const float* auxb = (const float*)d_in[30];
  float* out = (float*)d_out;

  char* ws = (char*)d_ws;
  size_t off = 0;
  auto alloc = [&](size_t bytes) -> void* {
    void* p = ws + off;
    off += (bytes + 255) & ~(size_t)255;
    return p;
  };
  _Float16* X0R = (_Float16*)alloc((size_t)N_NODES * 512 * 2); // layer1 GEMM out [gat1|residual] (fp16)
  _Float16* X0  = (_Float16*)alloc((size_t)N_NODES * HC * 2);  // layer2/3 GEMM out (fp16)
  _Float16* X1  = (_Float16*)alloc((size_t)N_NODES * HC * 2);  // agg output (fp16)
  ushort* Xb    = (ushort*)alloc((size_t)N_NODES * HC * 2);    // bf16 activations
  float*  as_   = (float*)alloc((size_t)N_NODES * NH * 4);
  float*  ad_   = (float*)alloc((size_t)N_NODES * NH * 4);
  float*  stats = (float*)alloc(512 * 4);
  float*  part  = (float*)alloc((size_t)AGG_BLOCKS * 512 * 4); // 4 MB BN partials
  int* cnt      = (int*)alloc((size_t)N_NODES * 4);
  int* rowptr   = (int*)alloc((size_t)(N_NODES + 1) * 4);
  int* fillptr  = (int*)alloc((size_t)N_NODES * 4);
  int* srcs     = (int*)alloc((size_t)(N_NODES + N_EDGES) * 4);
  int* bsum     = (int*)alloc(256 * 4);
  ushort* WtP   = (ushort*)alloc(512 * 128 * 2);  // [gat1_Wt ; res_Wt]
  ushort* Wt2   = (ushort*)alloc(256 * 256 * 2);
  ushort* Wt3   = (ushort*)alloc(256 * 256 * 2);
  ushort* Wth   = (ushort*)alloc(128 * 256 * 2);

  const int NB = (N_NODES + 255) / 256;
  // CSR build
  k_init_cnt<<<NB, 256, 0, stream>>>(cnt);
  k_count<<<(N_EDGES + 255) / 256, 256, 0, stream>>>(ei + N_EDGES, cnt);
  k_scan_bsum<<<NB, 256, 0, stream>>>(cnt, bsum);
  k_scan_offsets<<<1, 256, 0, stream>>>(bsum, NB);
  k_scan_write<<<NB, 256, 0, stream>>>(cnt, bsum, rowptr, fillptr);
  k_fill<<<(N_NODES + N_EDGES + 255) / 256, 256, 0, stream>>>(ei, ei + N_EDGES, fillptr, srcs);

  // weight prep (one kernel) + x -> bf16
  k_prep<<<320, 256, 0, stream>>>(gW[0], resW, gW[1], gW[2], muW, lvW, auxW, WtP, Wt2, Wt3, Wth);
  k_cvt_x<<<(N_NODES * 128) / 1024, 256, 0, stream>>>(x, Xb);

  const int GM = (N_NODES + 127) / 128;  // 391
  const int EW_GRID = (N_NODES * HC) / 2048;  // 6250

  // layer 1 + residual fused (+ att epilogue on cols 0-255); N=512 -> 8 col-tiles
  k_gemm_bf16<128, _Float16><<<dim3(GM, 8), 256, 0, stream>>>(
      Xb, WtP, resb, 256, X0R, N_NODES, 512, gasrc[0], gadst[0], as_, ad_);
  k_agg<<<AGG_BLOCKS, 256, 0, stream>>>(rowptr, srcs, as_, ad_, X0R, 512, gbias[0], X1, part, stats);
  k_bn_reduce<<<16, 256, 0, stream>>>(part, stats);
  k_bn_relu_cvt<<<EW_GRID, 256, 0, stream>>>(X1, stats, bng[0], bnb[0], nullptr, 0, Xb);

  // layers 2, 3 (+ att epilogue); N=256 -> 4 col-tiles
  const ushort* Wts[2] = {Wt2, Wt3};
  for (int L = 0; L < 2; L++) {
    k_gemm_bf16<256, _Float16><<<dim3(GM, 4), 256, 0, stream>>>(
        Xb, Wts[L], nullptr, 0, X0, N_NODES, 256, gasrc[L + 1], gadst[L + 1], as_, ad_);
    k_agg<<<AGG_BLOCKS, 256, 0, stream>>>(rowptr, srcs, as_, ad_, X0, 256, gbias[L + 1], X1, part, stats);
    k_bn_reduce<<<16, 256, 0, stream>>>(part, stats);
    k_bn_relu_cvt<<<EW_GRID, 256, 0, stream>>>(
        X1, stats, bng[L + 1], bnb[L + 1], (L == 1) ? (X0R + 256) : nullptr, 512, Xb);
  }
  // head GEMM + fused decode epilogue
  k_gemm_head<<<GM, 256, 0, stream>>>(Xb, Wth, eps, mub, lvb, auxb, decW, decb, out);
}

// Round 13
// 606.138 us; speedup vs baseline: 1.7580x; 1.0458x over previous
//
#include <hip/hip_runtime.h>

#define N_NODES 50000
#define N_EDGES 600000
#define HC 256
#define NH 8
#define AGG_BLOCKS 2048
#define AGG_WAVES (AGG_BLOCKS * 4)

typedef short s8v __attribute__((ext_vector_type(8)));
typedef float f4v __attribute__((ext_vector_type(4)));
typedef _Float16 h4v __attribute__((ext_vector_type(4)));
typedef _Float16 h8v __attribute__((ext_vector_type(8)));
typedef __attribute__((address_space(1))) const unsigned int as1_cu32;
typedef __attribute__((address_space(3))) unsigned int as3_u32;

__device__ inline ushort f2bf(float f) {
  unsigned u = __float_as_uint(f);
  unsigned r = u + 0x7FFF + ((u >> 16) & 1);  // RNE
  return (ushort)(r >> 16);
}

// ---------------------------------------------------------------- CSR build
__global__ void k_init_cnt(int* __restrict__ cnt) {
  int i = blockIdx.x * 256 + threadIdx.x;
  if (i < N_NODES) cnt[i] = 1;  // self-loop
}

__global__ void k_count(const int* __restrict__ dstE, int* __restrict__ cnt) {
  int e = blockIdx.x * 256 + threadIdx.x;
  if (e < N_EDGES) atomicAdd(&cnt[dstE[e]], 1);
}

__global__ void k_scan_bsum(const int* __restrict__ cnt, int* __restrict__ bsum) {
  __shared__ int sd[256];
  int i = blockIdx.x * 256 + threadIdx.x;
  sd[threadIdx.x] = (i < N_NODES) ? cnt[i] : 0;
  __syncthreads();
  for (int o = 128; o > 0; o >>= 1) {
    if (threadIdx.x < o) sd[threadIdx.x] += sd[threadIdx.x + o];
    __syncthreads();
  }
  if (threadIdx.x == 0) bsum[blockIdx.x] = sd[0];
}

__global__ void k_scan_offsets(int* __restrict__ bsum, int nb) {
  __shared__ int s[256];
  int t = threadIdx.x;
  int v = (t < nb) ? bsum[t] : 0;
  s[t] = v; __syncthreads();
  for (int o = 1; o < 256; o <<= 1) {
    int x = (t >= o) ? s[t - o] : 0;
    __syncthreads();
    s[t] += x;
    __syncthreads();
  }
  if (t < nb) bsum[t] = s[t] - v;  // exclusive
}

__global__ void k_scan_write(const int* __restrict__ cnt, const int* __restrict__ bsum,
                             int* __restrict__ rowptr, int* __restrict__ fillptr) {
  __shared__ int s[256];
  int t = threadIdx.x;
  int i = blockIdx.x * 256 + t;
  int v = (i < N_NODES) ? cnt[i] : 0;
  s[t] = v; __syncthreads();
  for (int o = 1; o < 256; o <<= 1) {
    int x = (t >= o) ? s[t - o] : 0;
    __syncthreads();
    s[t] += x;
    __syncthreads();
  }
  int excl = s[t] - v + bsum[blockIdx.x];
  if (i < N_NODES) {
    rowptr[i] = excl;
    fillptr[i] = excl;
    if (i == N_NODES - 1) rowptr[N_NODES] = excl + v;
  }
}

__global__ void k_fill(const int* __restrict__ srcE, const int* __restrict__ dstE,
                       int* __restrict__ fillptr, int* __restrict__ srcs) {
  int i = blockIdx.x * 256 + threadIdx.x;
  if (i < N_NODES) {
    int pos = atomicAdd(&fillptr[i], 1);
    srcs[pos] = i;                       // self-loop
  } else if (i < N_NODES + N_EDGES) {
    int e = i - N_NODES;
    int pos = atomicAdd(&fillptr[dstE[e]], 1);
    srcs[pos] = srcE[e];
  }
}

// ---------------------------------------------------------------- fp32 -> bf16 convert (x)
__global__ void k_cvt_x(const float* __restrict__ X, ushort* __restrict__ Xb) {
  size_t i = ((size_t)blockIdx.x * 256 + threadIdx.x) * 4;
  float4 x4 = *(const float4*)&X[i];
  ushort4 o;
  o.x = f2bf(x4.x); o.y = f2bf(x4.y); o.z = f2bf(x4.z); o.w = f2bf(x4.w);
  *(ushort4*)&Xb[i] = o;
}

// ---------------------------------------------------------------- all weight prep in ONE kernel
// blocks 0-31: gat1_W -> WtP[0:256]; 32-63: res_W -> WtP[256:512];
// 64-127: gat2_W -> Wt2; 128-191: gat3_W -> Wt3; 192-319: pack head -> Wth.
__global__ void k_prep(const float* __restrict__ gW0, const float* __restrict__ resW,
                       const float* __restrict__ gW1, const float* __restrict__ gW2,
                       const float* __restrict__ muW, const float* __restrict__ lvW,
                       const float* __restrict__ auxW,
                       ushort* __restrict__ WtP, ushort* __restrict__ Wt2,
                       ushort* __restrict__ Wt3, ushort* __restrict__ Wth) {
  __shared__ ushort s[32][33];
  int id = blockIdx.x;
  int t = threadIdx.x;
  if (id < 64) {                       // K=128 transposes into WtP
    const float* W = (id < 32) ? gW0 : resW;
    ushort* Wt = (id < 32) ? WtP : (WtP + 256 * 128);
    int a = id & 31;
    int bx = a & 3, by = a >> 2;       // grid (4,8)
    int tx = t & 31, ty = t >> 5;
    int k0 = bx * 32, n0 = by * 32;
    for (int j = 0; j < 32; j += 8)
      s[ty + j][tx] = f2bf(W[(size_t)(k0 + ty + j) * 256 + n0 + tx]);
    __syncthreads();
    for (int j = 0; j < 32; j += 8)
      Wt[(size_t)(n0 + ty + j) * 128 + k0 + tx] = s[tx][ty + j];
  } else if (id < 192) {               // K=256 transposes
    const float* W = (id < 128) ? gW1 : gW2;
    ushort* Wt = (id < 128) ? Wt2 : Wt3;
    int a = (id - 64) & 63;
    int bx = a & 7, by = a >> 3;       // grid (8,8)
    int tx = t & 31, ty = t >> 5;
    int k0 = bx * 32, n0 = by * 32;
    for (int j = 0; j < 32; j += 8)
      s[ty + j][tx] = f2bf(W[(size_t)(k0 + ty + j) * 256 + n0 + tx]);
    __syncthreads();
    for (int j = 0; j < 32; j += 8)
      Wt[(size_t)(n0 + ty + j) * 256 + k0 + tx] = s[tx][ty + j];
  } else {                             // pack [muW|lvW|auxW|0] -> Wth[128][256]
    int n = id - 192;                  // 0..127
    int k = t;                         // 0..255
    float v = 0.f;
    if (n < 32) v = muW[k * 32 + n];
    else if (n < 64) v = lvW[k * 32 + (n - 32)];
    else if (n < 94) v = auxW[k * 30 + (n - 64)];
    Wth[n * 256 + k] = f2bf(v);
  }
}

// ---------------------------------------------------------------- bf16 MFMA GEMM, 128x64 tile
// Half-width N-tile: LDS 24KB -> ~5-6 resident blocks/CU to overlap the
// short-nk barrier-drain K-loop (proven round 9; barrier-free and BN-fused
// variants both regressed -- rounds 10/12).
// bias_off: cols < bias_off get 0, cols >= bias_off get bias[col - bias_off].
// Fused att epilogue: 64-col tile = 2 complete heads, one head per wave.
template <typename OutT>
__launch_bounds__(256)
__global__ void k_gemm_bf16(const ushort* __restrict__ A, const ushort* __restrict__ Wt,
                            const float* __restrict__ bias, int bias_off, OutT* __restrict__ Out,
                            int M, int K, int ldc,
                            const float* __restrict__ att_asrc, const float* __restrict__ att_adst,
                            float* __restrict__ att_as, float* __restrict__ att_ad) {
  __shared__ __align__(16) ushort As[16 * 512];  // 16 KB (A: 128 rows)
  __shared__ __align__(16) ushort Bs[8 * 512];   //  8 KB (B:  64 rows)
  int t = threadIdx.x, w = t >> 6, L = t & 63;
  int bm = blockIdx.x * 128, bn = blockIdx.y * 64;
  int lrow = L & 15, lcol = (L >> 4) * 8;

  const ushort* ga[4];
  const ushort* gb[2];
#pragma unroll
  for (int u = 0; u < 4; u++) {
    int i = w * 4 + u;
    int mt = i >> 1, ks = i & 1;
    int arow = bm + mt * 16 + lrow;
    if (arow >= M) arow = M - 1;
    ga[u] = A + (size_t)arow * K + ks * 32 + lcol;
  }
#pragma unroll
  for (int u = 0; u < 2; u++) {
    int i = w * 2 + u;
    int mt = i >> 1, ks = i & 1;
    int brow = bn + mt * 16 + lrow;
    gb[u] = Wt + (size_t)brow * K + ks * 32 + lcol;
  }

  f4v acc[4][2];
  f4v zero = {0.f, 0.f, 0.f, 0.f};
#pragma unroll
  for (int mi = 0; mi < 4; mi++)
#pragma unroll
    for (int ni = 0; ni < 2; ni++) acc[mi][ni] = zero;

  int wm = (w >> 1) * 4;
  int wn = (w & 1) * 2;

  int nk = K >> 6;
  for (int kt = 0; kt < nk; kt++) {
#pragma unroll
    for (int u = 0; u < 4; u++) {
      int i = w * 4 + u;
      __builtin_amdgcn_global_load_lds((as1_cu32*)ga[u], (as3_u32*)&As[i * 512], 16, 0, 0);
      ga[u] += 64;
    }
#pragma unroll
    for (int u = 0; u < 2; u++) {
      int i = w * 2 + u;
      __builtin_amdgcn_global_load_lds((as1_cu32*)gb[u], (as3_u32*)&Bs[i * 512], 16, 0, 0);
      gb[u] += 64;
    }
    __syncthreads();
#pragma unroll
    for (int ks = 0; ks < 2; ks++) {
      s8v af[4], bf[2];
#pragma unroll
      for (int mi = 0; mi < 4; mi++)
        af[mi] = *(const s8v*)&As[(((wm + mi) * 2 + ks) * 64 + L) * 8];
#pragma unroll
      for (int ni = 0; ni < 2; ni++)
        bf[ni] = *(const s8v*)&Bs[(((wn + ni) * 2 + ks) * 64 + L) * 8];
#pragma unroll
      for (int mi = 0; mi < 4; mi++)
#pragma unroll
        for (int ni = 0; ni < 2; ni++)
          acc[mi][ni] = __builtin_amdgcn_mfma_f32_16x16x32_bf16(af[mi], bf[ni], acc[mi][ni], 0, 0, 0);
    }
    __syncthreads();
  }
#pragma unroll
  for (int ni = 0; ni < 2; ni++) {
    int col = bn + (wn + ni) * 16 + (L & 15);
    float bb = (bias && col >= bias_off) ? bias[col - bias_off] : 0.f;
#pragma unroll
    for (int mi = 0; mi < 4; mi++) {
      int rbase = bm + (wm + mi) * 16 + (L >> 4) * 4;
#pragma unroll
      for (int i = 0; i < 4; i++) {
        int r = rbase + i;
        if (r < M) Out[(size_t)r * ldc + col] = (OutT)(acc[mi][ni][i] + bb);
      }
    }
  }
  // ---- fused attention logits (one complete head per wave) ----
  if (att_as && bn < 256) {
    int hb = ((unsigned)(bn + wn * 16)) >> 5;   // wave's head
    int cl = L & 15;
    float sa0 = att_asrc[hb * 32 + cl],  sa1 = att_asrc[hb * 32 + 16 + cl];
    float da0 = att_adst[hb * 32 + cl],  da1 = att_adst[hb * 32 + 16 + cl];
#pragma unroll
    for (int mi = 0; mi < 4; mi++) {
#pragma unroll
      for (int i = 0; i < 4; i++) {
        float vs = acc[mi][0][i] * sa0 + acc[mi][1][i] * sa1;
        float vd = acc[mi][0][i] * da0 + acc[mi][1][i] * da1;
        vs += __shfl_xor(vs, 1); vd += __shfl_xor(vd, 1);
        vs += __shfl_xor(vs, 2); vd += __shfl_xor(vd, 2);
        vs += __shfl_xor(vs, 4); vd += __shfl_xor(vd, 4);
        vs += __shfl_xor(vs, 8); vd += __shfl_xor(vd, 8);
        int r = bm + (wm + mi) * 16 + (L >> 4) * 4 + i;
        if (cl == 0 && r < M) {
          att_as[r * NH + hb] = vs;
          att_ad[r * NH + hb] = vd;
        }
      }
    }
  }
}

// ---------------------------------------------------------------- head GEMM + fused decode
__launch_bounds__(256)
__global__ void k_gemm_head(const ushort* __restrict__ A, const ushort* __restrict__ Wt,
                            const float* __restrict__ eps,
                            const float* __restrict__ mub, const float* __restrict__ lvb,
                            const float* __restrict__ auxb,
                            const float* __restrict__ decW, const float* __restrict__ decb,
                            float* __restrict__ out) {
  __shared__ __align__(16) ushort smem[16384];   // As | Bs during loop; fp16 tile after
  __shared__ float wsd[2048];                    // decW [32][64]
  __shared__ float shz[4][32];
  ushort* As = smem;
  ushort* Bs = smem + 8192;
  int t = threadIdx.x, w = t >> 6, L = t & 63;
  int bm = blockIdx.x * 128;
  int lrow = L & 15, lcol = (L >> 4) * 8;
  const int K = 256;
  for (int i = t; i < 2048; i += 256) wsd[i] = decW[i];

  const ushort* ga[4];
  const ushort* gb[4];
#pragma unroll
  for (int u = 0; u < 4; u++) {
    int i = w * 4 + u;
    int mt = i >> 1, ks = i & 1;
    int arow = bm + mt * 16 + lrow;
    if (arow >= N_NODES) arow = N_NODES - 1;
    ga[u] = A + (size_t)arow * K + ks * 32 + lcol;
    int brow = mt * 16 + lrow;                   // bn = 0, 128 rows of Wth
    gb[u] = Wt + (size_t)brow * K + ks * 32 + lcol;
  }
  f4v acc[4][4];
  f4v zero = {0.f, 0.f, 0.f, 0.f};
#pragma unroll
  for (int mi = 0; mi < 4; mi++)
#pragma unroll
    for (int ni = 0; ni < 4; ni++) acc[mi][ni] = zero;
  int wm = (w >> 1) * 4;
  int wn = (w & 1) * 4;
  for (int kt = 0; kt < 4; kt++) {
#pragma unroll
    for (int u = 0; u < 4; u++) {
      int i = w * 4 + u;
      __builtin_amdgcn_global_load_lds((as1_cu32*)ga[u], (as3_u32*)&As[i * 512], 16, 0, 0);
      __builtin_amdgcn_global_load_lds((as1_cu32*)gb[u], (as3_u32*)&Bs[i * 512], 16, 0, 0);
      ga[u] += 64; gb[u] += 64;
    }
    __syncthreads();
#pragma unroll
    for (int ks = 0; ks < 2; ks++) {
      s8v af[4], bf[4];
#pragma unroll
      for (int mi = 0; mi < 4; mi++)
        af[mi] = *(const s8v*)&As[(((wm + mi) * 2 + ks) * 64 + L) * 8];
#pragma unroll
      for (int ni = 0; ni < 4; ni++)
        bf[ni] = *(const s8v*)&Bs[(((wn + ni) * 2 + ks) * 64 + L) * 8];
#pragma unroll
      for (int mi = 0; mi < 4; mi++)
#pragma unroll
        for (int ni = 0; ni < 4; ni++)
          acc[mi][ni] = __builtin_amdgcn_mfma_f32_16x16x32_bf16(af[mi], bf[ni], acc[mi][ni], 0, 0, 0);
    }
    __syncthreads();
  }
  // stash acc -> fp16 tile [128][128] overlaying As/Bs
  _Float16* tile = (_Float16*)smem;
#pragma unroll
  for (int ni = 0; ni < 4; ni++) {
    int c = (wn + ni) * 16 + (L & 15);
#pragma unroll
    for (int mi = 0; mi < 4; mi++) {
      int rbase = (wm + mi) * 16 + (L >> 4) * 4;
#pragma unroll
      for (int i = 0; i < 4; i++)
        tile[(rbase + i) * 128 + c] = (_Float16)acc[mi][ni][i];
    }
  }
  __syncthreads();
  // decode: each wave handles 32 consecutive rows
  for (int rr = 0; rr < 32; rr++) {
    int rl = w * 32 + rr;
    int n = bm + rl;
    bool valid = n < N_NODES;
    if (L < 32) {
      float mu = (float)tile[rl * 128 + L] + mub[L];
      float lv = (float)tile[rl * 128 + 32 + L] + lvb[L];
      float zv = 0.f;
      if (valid) {
        out[(size_t)N_NODES * 64 + (size_t)n * 32 + L] = mu;
        out[(size_t)N_NODES * 96 + (size_t)n * 32 + L] = lv;
        zv = mu + eps[(size_t)n * 32 + L] * __expf(0.5f * lv);
      }
      shz[w][L] = zv;
    } else if (L < 62 && valid) {
      int j = L - 32;
      out[(size_t)N_NODES * 128 + (size_t)n * 30 + j] = (float)tile[rl * 128 + 64 + j] + auxb[j];
    }
    __syncthreads();
    float o = decb[L];
#pragma unroll 8
    for (int kk = 0; kk < 32; kk++) o += shz[w][kk] * wsd[kk * 64 + L];
    if (valid) out[(size_t)n * 64 + L] = o;
    __syncthreads();
  }
}

// ---------------------------------------------------------------- aggregate (single pass) + BN partials
// At its fabric floor: 333MB logical gather in ~58us = ~6.1 TB/s delivered.
#define FMA4(P, B2)                                                                        \
  asm("v_fma_mix_f32 %0, %1, %2, %0 op_sel:[0,0,0] op_sel_hi:[0,1,0]"                      \
      : "+v"(ac0) : "v"(P), "v"((B2).x));                                                  \
  asm("v_fma_mix_f32 %0, %1, %2, %0 op_sel:[0,1,0] op_sel_hi:[0,1,0]"                      \
      : "+v"(ac1) : "v"(P), "v"((B2).x));                                                  \
  asm("v_fma_mix_f32 %0, %1, %2, %0 op_sel:[0,0,0] op_sel_hi:[0,1,0]"                      \
      : "+v"(ac2) : "v"(P), "v"((B2).y));                                                  \
  asm("v_fma_mix_f32 %0, %1, %2, %0 op_sel:[0,1,0] op_sel_hi:[0,1,0]"                      \
      : "+v"(ac3) : "v"(P), "v"((B2).y));

__launch_bounds__(256)
__global__ void k_agg(const int* __restrict__ rowptr, const int* __restrict__ srcs,
                      const float* __restrict__ as_, const float* __restrict__ ad_,
                      const _Float16* __restrict__ B, int ld, const float* __restrict__ gb,
                      _Float16* __restrict__ C, float* __restrict__ part,
                      float* __restrict__ stats) {
  __shared__ float ss[4 * 512];
  int t = threadIdx.x;
  if (blockIdx.x == 0) {  // fold stats zeroing (consumed only by k_bn_reduce, after this kernel)
    stats[t] = 0.f; stats[t + 256] = 0.f;
  }
  int w = t >> 6, lane = t & 63;
  int h = lane >> 3;
  int cb = lane << 2;     // 4 channels per lane
  int ldu = ld >> 2;      // row stride in uint2 (8B) units
  const uint2* Bu = (const uint2*)B;
  float4 g4 = *(const float4*)&gb[cb];
  float sts0 = 0.f, sts1 = 0.f, sts2 = 0.f, sts3 = 0.f;
  float stq0 = 0.f, stq1 = 0.f, stq2 = 0.f, stq3 = 0.f;

  for (int n = blockIdx.x * 4 + w; n < N_NODES; n += AGG_WAVES) {
    int beg = rowptr[n], end = rowptr[n + 1];
    float ad_nh = ad_[n * NH + h];
    float ac0 = 0.f, ac1 = 0.f, ac2 = 0.f, ac3 = 0.f, wsum = 0.f;
    int k = beg;
    for (; k + 4 <= end; k += 4) {
      int s0 = srcs[k], s1 = srcs[k + 1], s2 = srcs[k + 2], s3 = srcs[k + 3];
      uint2 b0 = Bu[(size_t)s0 * ldu + lane];
      uint2 b1 = Bu[(size_t)s1 * ldu + lane];
      uint2 b2 = Bu[(size_t)s2 * ldu + lane];
      uint2 b3 = Bu[(size_t)s3 * ldu + lane];
      float e0 = as_[s0 * NH + h] + ad_nh; e0 = e0 > 0.f ? e0 : 0.2f * e0;
      float e1 = as_[s1 * NH + h] + ad_nh; e1 = e1 > 0.f ? e1 : 0.2f * e1;
      float e2 = as_[s2 * NH + h] + ad_nh; e2 = e2 > 0.f ? e2 : 0.2f * e2;
      float e3 = as_[s3 * NH + h] + ad_nh; e3 = e3 > 0.f ? e3 : 0.2f * e3;
      float p0 = __expf(e0), p1 = __expf(e1), p2 = __expf(e2), p3 = __expf(e3);
      wsum += (p0 + p1) + (p2 + p3);
      FMA4(p0, b0)
      FMA4(p1, b1)
      FMA4(p2, b2)
      FMA4(p3, b3)
    }
    for (; k < end; k++) {
      int s = srcs[k];
      h4v b4 = *(const h4v*)&B[(size_t)s * ld + cb];
      float e = as_[s * NH + h] + ad_nh;
      e = e > 0.f ? e : 0.2f * e;
      float p = __expf(e);
      wsum += p;
      ac0 += p * (float)b4[0]; ac1 += p * (float)b4[1];
      ac2 += p * (float)b4[2]; ac3 += p * (float)b4[3];
    }
    float inv = 1.f / (wsum + 1e-16f);
    float v0 = ac0 * inv + g4.x, v1 = ac1 * inv + g4.y;
    float v2 = ac2 * inv + g4.z, v3 = ac3 * inv + g4.w;
    h4v o; o[0] = (_Float16)v0; o[1] = (_Float16)v1; o[2] = (_Float16)v2; o[3] = (_Float16)v3;
    *(h4v*)&C[(size_t)n * 256 + cb] = o;
    sts0 += v0; stq0 += v0 * v0;
    sts1 += v1; stq1 += v1 * v1;
    sts2 += v2; stq2 += v2 * v2;
    sts3 += v3; stq3 += v3 * v3;
  }
  // per-wave LDS slots (no atomics), cross-wave sum, plain store of partials
  float* sw = &ss[w * 512];
  sw[cb + 0] = sts0; sw[cb + 1] = sts1; sw[cb + 2] = sts2; sw[cb + 3] = sts3;
  sw[256 + cb + 0] = stq0; sw[256 + cb + 1] = stq1;
  sw[256 + cb + 2] = stq2; sw[256 + cb + 3] = stq3;
  __syncthreads();
  float p0 = ss[t] + ss[512 + t] + ss[1024 + t] + ss[1536 + t];
  float p1 = ss[256 + t] + ss[768 + t] + ss[1280 + t] + ss[1792 + t];
  part[(size_t)blockIdx.x * 512 + t] = p0;
  part[(size_t)blockIdx.x * 512 + 256 + t] = p1;
}

// reduce AGG_BLOCKS x 512 partials -> stats[512]; 16 blocks, tiny atomic fan-in
__global__ void k_bn_reduce(const float* __restrict__ part, float* __restrict__ stats) {
  int i = threadIdx.x;            // 0..255
  int base = blockIdx.x * (AGG_BLOCKS / 16);
  float s0 = 0.f, s1 = 0.f;
  for (int b = 0; b < AGG_BLOCKS / 16; b++) {
    s0 += part[(size_t)(base + b) * 512 + i];
    s1 += part[(size_t)(base + b) * 512 + 256 + i];
  }
  atomicAdd(&stats[i], s0);
  atomicAdd(&stats[256 + i], s1);
}

// BN + ReLU (+ optional fp16 residual add, row stride rld): fp16 in -> bf16 out
// 8 channels / thread (16B loads), grid = N*HC/2048
__global__ void k_bn_relu_cvt(const _Float16* __restrict__ X, const float* __restrict__ stats,
                              const float* __restrict__ g, const float* __restrict__ b,
                              const _Float16* __restrict__ resid, int rld,
                              ushort* __restrict__ Xb) {
  size_t i = ((size_t)blockIdx.x * 256 + threadIdx.x) * 8;
  int c = (int)(i & 255);
  const float invN = 1.f / (float)N_NODES;
  h8v x8 = *(const h8v*)&X[i];
  float v[8];
#pragma unroll
  for (int q = 0; q < 2; q++) {
    float4 s4 = *(const float4*)&stats[c + q * 4];
    float4 q4 = *(const float4*)&stats[256 + c + q * 4];
    float4 g4 = *(const float4*)&g[c + q * 4];
    float4 b4 = *(const float4*)&b[c + q * 4];
    float m0 = s4.x * invN, m1 = s4.y * invN, m2 = s4.z * invN, m3 = s4.w * invN;
    v[q * 4 + 0] = ((float)x8[q * 4 + 0] - m0) * rsqrtf(q4.x * invN - m0 * m0 + 1e-5f) * g4.x + b4.x;
    v[q * 4 + 1] = ((float)x8[q * 4 + 1] - m1) * rsqrtf(q4.y * invN - m1 * m1 + 1e-5f) * g4.y + b4.y;
    v[q * 4 + 2] = ((float)x8[q * 4 + 2] - m2) * rsqrtf(q4.z * invN - m2 * m2 + 1e-5f) * g4.z + b4.z;
    v[q * 4 + 3] = ((float)x8[q * 4 + 3] - m3) * rsqrtf(q4.w * invN - m3 * m3 + 1e-5f) * g4.w + b4.w;
  }
#pragma unroll
  for (int q = 0; q < 8; q++) v[q] = v[q] > 0.f ? v[q] : 0.f;
  if (resid) {
    size_t row = i >> 8;
    h8v r8 = *(const h8v*)&resid[row * rld + c];
#pragma unroll
    for (int q = 0; q < 8; q++) v[q] += (float)r8[q];
  }
  ushort o8[8];
#pragma unroll
  for (int q = 0; q < 8; q++) o8[q] = f2bf(v[q]);
  *(uint4*)&Xb[i] = *(const uint4*)o8;
}

// ---------------------------------------------------------------- launch
extern "C" void kernel_launch(void* const* d_in, const int* in_sizes, int n_in,
                              void* d_out, int out_size, void* d_ws, size_t ws_size,
                              hipStream_t stream) {
  (void)in_sizes; (void)n_in; (void)out_size; (void)ws_size;
  const float* x    = (const float*)d_in[0];
  const float* eps  = (const float*)d_in[1];
  const int*   ei   = (const int*)d_in[2];
  const float* gW[3]    = {(const float*)d_in[3],  (const float*)d_in[9],  (const float*)d_in[15]};
  const float* gasrc[3] = {(const float*)d_in[4],  (const float*)d_in[10], (const float*)d_in[16]};
  const float* gadst[3] = {(const float*)d_in[5],  (const float*)d_in[11], (const float*)d_in[17]};
  const float* gbias[3] = {(const float*)d_in[6],  (const float*)d_in[12], (const float*)d_in[18]};
  const float* bng[3]   = {(const float*)d_in[7],  (const float*)d_in[13], (const float*)d_in[19]};
  const float* bnb[3]   = {(const float*)d_in[8],  (const float*)d_in[14], (const float*)d_in[20]};
  const float* resW = (const float*)d_in[21];
  const float* resb = (const float*)d_in[22];
  const float* muW  = (const float*)d_in[23];
  const float* mub  = (const float*)d_in[24];
  const float* lvW  = (const float*)d_in[25];
  const float* lvb  = (const float*)d_in[26];
  const float* decW = (const float*)d_in[27];
  const float* decb = (const float*)d_in[28];
  const float* auxW = (const float*)d_in[29];
  const float* auxb = (const float*)d_in[30];
  float* out = (float*)d_out;

  char* ws = (char*)d_ws;
  size_t off = 0;
  auto alloc = [&](size_t bytes) -> void* {
    void* p = ws + off;
    off += (bytes + 255) & ~(size_t)255;
    return p;
  };
  _Float16* X0R = (_Float16*)alloc((size_t)N_NODES * 512 * 2); // layer1 GEMM out [gat1|residual] (fp16)
  _Float16* X0  = (_Float16*)alloc((size_t)N_NODES * HC * 2);  // layer2/3 GEMM out (fp16)
  _Float16* X1  = (_Float16*)alloc((size_t)N_NODES * HC * 2);  // agg output (fp16)
  ushort* Xb    = (ushort*)alloc((size_t)N_NODES * HC * 2);    // bf16 activations
  float*  as_   = (float*)alloc((size_t)N_NODES * NH * 4);
  float*  ad_   = (float*)alloc((size_t)N_NODES * NH * 4);
  float*  stats = (float*)alloc(512 * 4);
  float*  part  = (float*)alloc((size_t)AGG_BLOCKS * 512 * 4); // 4 MB BN partials
  int* cnt      = (int*)alloc((size_t)N_NODES * 4);
  int* rowptr   = (int*)alloc((size_t)(N_NODES + 1) * 4);
  int* fillptr  = (int*)alloc((size_t)N_NODES * 4);
  int* srcs     = (int*)alloc((size_t)(N_NODES + N_EDGES) * 4);
  int* bsum     = (int*)alloc(256 * 4);
  ushort* WtP   = (ushort*)alloc(512 * 128 * 2);  // [gat1_Wt ; res_Wt]
  ushort* Wt2   = (ushort*)alloc(256 * 256 * 2);
  ushort* Wt3   = (ushort*)alloc(256 * 256 * 2);
  ushort* Wth   = (ushort*)alloc(128 * 256 * 2);

  const int NB = (N_NODES + 255) / 256;
  // CSR build
  k_init_cnt<<<NB, 256, 0, stream>>>(cnt);
  k_count<<<(N_EDGES + 255) / 256, 256, 0, stream>>>(ei + N_EDGES, cnt);
  k_scan_bsum<<<NB, 256, 0, stream>>>(cnt, bsum);
  k_scan_offsets<<<1, 256, 0, stream>>>(bsum, NB);
  k_scan_write<<<NB, 256, 0, stream>>>(cnt, bsum, rowptr, fillptr);
  k_fill<<<(N_NODES + N_EDGES + 255) / 256, 256, 0, stream>>>(ei, ei + N_EDGES, fillptr, srcs);

  // weight prep (one kernel) + x -> bf16
  k_prep<<<320, 256, 0, stream>>>(gW[0], resW, gW[1], gW[2], muW, lvW, auxW, WtP, Wt2, Wt3, Wth);
  k_cvt_x<<<(N_NODES * 128) / 1024, 256, 0, stream>>>(x, Xb);

  const int GM = (N_NODES + 127) / 128;  // 391
  const int EW_GRID = (N_NODES * HC) / 2048;  // 6250

  // layer 1 + residual fused (+ att epilogue on cols 0-255); N=512 -> 8 col-tiles
  k_gemm_bf16<_Float16><<<dim3(GM, 8), 256, 0, stream>>>(
      Xb, WtP, resb, 256, X0R, N_NODES, 128, 512, gasrc[0], gadst[0], as_, ad_);
  k_agg<<<AGG_BLOCKS, 256, 0, stream>>>(rowptr, srcs, as_, ad_, X0R, 512, gbias[0], X1, part, stats);
  k_bn_reduce<<<16, 256, 0, stream>>>(part, stats);
  k_bn_relu_cvt<<<EW_GRID, 256, 0, stream>>>(X1, stats, bng[0], bnb[0], nullptr, 0, Xb);

  // layers 2, 3 (+ att epilogue); N=256 -> 4 col-tiles
  const ushort* Wts[2] = {Wt2, Wt3};
  for (int L = 0; L < 2; L++) {
    k_gemm_bf16<_Float16><<<dim3(GM, 4), 256, 0, stream>>>(
        Xb, Wts[L], nullptr, 0, X0, N_NODES, 256, 256, gasrc[L + 1], gadst[L + 1], as_, ad_);
    k_agg<<<AGG_BLOCKS, 256, 0, stream>>>(rowptr, srcs, as_, ad_, X0, 256, gbias[L + 1], X1, part, stats);
    k_bn_reduce<<<16, 256, 0, stream>>>(part, stats);
    k_bn_relu_cvt<<<EW_GRID, 256, 0, stream>>>(
        X1, stats, bng[L + 1], bnb[L + 1], (L == 1) ? (X0R + 256) : nullptr, 512, Xb);
  }
  // head GEMM + fused decode epilogue
  k_gemm_head<<<GM, 256, 0, stream>>>(Xb, Wth, eps, mub, lvb, auxb, decW, decb, out);
}